// Round 9
// baseline (311.086 us; speedup 1.0000x reference)
//
#include <hip/hip_runtime.h>
#include <math.h>

typedef __bf16 bf16;
typedef __attribute__((ext_vector_type(8))) __bf16 bf16x8;
typedef __attribute__((ext_vector_type(4))) __bf16 bf16x4;
typedef __attribute__((ext_vector_type(4))) float f32x4;

#define BB 2
#define TT 2048
#define DD 1024
#define NHD 16
#define HD 64
#define MM (BB*TT)          // 4096
#define LOG2E_F 1.442695041f
#define NEGINF_F (-1.0e9f)

// async global->LDS, 16B per lane; LDS dest must be wave-uniform base
__device__ __forceinline__ void gld16(const bf16* g, bf16* l)
{
    __builtin_amdgcn_global_load_lds(
        (const __attribute__((address_space(1))) unsigned int*)g,
        (__attribute__((address_space(3))) unsigned int*)l, 16, 0, 0);
}

// ---------------------------------------------------------------------------
// fused prep: [0,4096) split_x; [4096,8192) weight transpose/convert;
// [8192,12288) mask -> ADDITIVE bf16 mask (0 or -1e9), written into d_out
// (16 MB, exactly out_size; dead until gemm_out overwrites it).
// NOTE (R7 lesson): sigma(S) ~ 1500 in exp2 domain (q,k entries are sigma=32,
// not O(1)) -> a fixed softmax shift overflows; running max is mandatory.
// ---------------------------------------------------------------------------
__global__ __launch_bounds__(256)
void prep_all(const float* __restrict__ X, const int* __restrict__ m,
              const float* __restrict__ wq, const float* __restrict__ wk,
              const float* __restrict__ wv, const float* __restrict__ wo,
              bf16* __restrict__ Xh, bf16* __restrict__ Xl,
              bf16* __restrict__ qkh, bf16* __restrict__ qkl,
              bf16* __restrict__ vh, bf16* __restrict__ ob,
              bf16* __restrict__ madd)
{
    __shared__ float tile[32][33];
    const int bid = blockIdx.x;
    const int t   = threadIdx.x;

    if (bid < 4096) {                         // split X -> hi/lo
        int i = bid * 256 + t;
        float4 v = ((const float4*)X)[i];
        float f[4] = {v.x, v.y, v.z, v.w};
        bf16x4 h, l;
        #pragma unroll
        for (int j = 0; j < 4; ++j) {
            bf16 hh = (bf16)f[j];
            h[j] = hh;
            l[j] = (bf16)(f[j] - (float)hh);
        }
        *(bf16x4*)(Xh + (size_t)i * 4) = h;
        *(bf16x4*)(Xl + (size_t)i * 4) = l;
        return;
    }
    if (bid < 8192) {                         // weights
        const int idx = bid - 4096;
        const int z   = idx >> 10;            // 0:wq 1:wk 2:wv 3:wo
        const int bx  = (idx & 31) << 5;      // nh block
        const int by  = ((idx >> 5) & 31) << 5;  // d block
        const int r   = t >> 3;
        const int c4  = (t & 7) << 2;
        if (z == 3) {
            float4 v = *(const float4*)(wo + (size_t)(by + r) * 1024 + bx + c4);
            bf16x4 o = { (bf16)v.x, (bf16)v.y, (bf16)v.z, (bf16)v.w };
            *(bf16x4*)(ob + (size_t)(by + r) * 1024 + bx + c4) = o;
            return;
        }
        const float* src = (z == 0) ? wq : ((z == 1) ? wk : wv);
        bf16* oh = (z == 0) ? qkh : ((z == 1) ? qkh + 1048576 : vh);
        bf16* ol = (z == 0) ? qkl : ((z == 1) ? qkl + 1048576 : nullptr);
        float4 v = *(const float4*)(src + (size_t)(by + r) * 1024 + bx + c4);
        tile[r][c4+0] = v.x; tile[r][c4+1] = v.y;
        tile[r][c4+2] = v.z; tile[r][c4+3] = v.w;
        __syncthreads();
        bf16x4 hv, lv;
        #pragma unroll
        for (int j = 0; j < 4; ++j) {
            float f = tile[c4 + j][r];
            bf16 h = (bf16)f;
            hv[j] = h;
            lv[j] = (bf16)(f - (float)h);
        }
        *(bf16x4*)(oh + (size_t)(bx + r) * 1024 + by + c4) = hv;
        if (ol)
            *(bf16x4*)(ol + (size_t)(bx + r) * 1024 + by + c4) = lv;
        return;
    }
    {                                         // mask -> additive bf16
        int i = (bid - 8192) * 256 + t;       // i < 1048576 (8 elems each)
        const int4* mp = (const int4*)m + (size_t)i * 2;
        int4 a  = mp[0];
        int4 b4 = mp[1];
        bf16x8 o;
        o[0] = (bf16)(a.x  ? 0.f : NEGINF_F);
        o[1] = (bf16)(a.y  ? 0.f : NEGINF_F);
        o[2] = (bf16)(a.z  ? 0.f : NEGINF_F);
        o[3] = (bf16)(a.w  ? 0.f : NEGINF_F);
        o[4] = (bf16)(b4.x ? 0.f : NEGINF_F);
        o[5] = (bf16)(b4.y ? 0.f : NEGINF_F);
        o[6] = (bf16)(b4.z ? 0.f : NEGINF_F);
        o[7] = (bf16)(b4.w ? 0.f : NEGINF_F);
        *(bf16x8*)(madd + (size_t)i * 8) = o;
    }
}

// ---------------------------------------------------------------------------
// Fused projection GEMM, retiled for occupancy (R9): 128x64 tiles.
//  [0,1024): QK — 3-pass split (Xh*Wh + Xh*Wl + Xl*Wh), 128(bt)x64(nh'),
//            BK=32; col<1024 -> Q (scaled, exp2-domain), else K; hi/lo out.
//  [1024,1536): V — C^T = Wvh · Xh^T, 128(nh)x64(bt), out Vt + bias.
// Grid 1536 = 6 blocks/CU (was 768 = 3/CU, Occupancy 19%); LDS 24 KB.
// XCD-swizzled (T1) within each segment.
// ---------------------------------------------------------------------------
__global__ __launch_bounds__(256)
void gemm_proj(const bf16* __restrict__ Xh, const bf16* __restrict__ Xl,
               const bf16* __restrict__ Wh, const bf16* __restrict__ Wl,
               const bf16* __restrict__ Wvh,
               const float* __restrict__ bq, const float* __restrict__ bk,
               const float* __restrict__ bv, const float* __restrict__ pds,
               bf16* __restrict__ oQh, bf16* __restrict__ oQl,
               bf16* __restrict__ oKh, bf16* __restrict__ oKl,
               bf16* __restrict__ oVt)
{
    __shared__ bf16 SA[2][128 * 32];   // A hi/lo: 16 KB
    __shared__ bf16 SB[2][64 * 32];    // B hi/lo:  8 KB

    int bid = blockIdx.x;
    // bijective XCD swizzle within each segment (8 XCDs)
    if (bid < 1024) bid = ((bid & 7) << 7) + (bid >> 3);
    else {
        int idx = bid - 1024;
        bid = 1024 + (((idx & 7) << 6) + (idx >> 3));
    }

    const int t    = threadIdx.x;
    const int lane = t & 63;
    const int w    = t >> 6;
    const int quad = lane >> 4, l15 = lane & 15;
    const int wm   = (w >> 1) << 6;    // 0 / 64
    const int wn   = (w & 1)  << 5;    // 0 / 32

    const int jr0 = ((w * 2 + 0) << 4) + (lane >> 2);   // A rows, site 0
    const int jr1 = ((w * 2 + 1) << 4) + (lane >> 2);   // A rows, site 1
    const int jrB = (w << 4) + (lane >> 2);             // B rows (64)
    const int kch = (lane & 3) << 3;
    const int offA0 = (w * 2 + 0) * 512;
    const int offA1 = (w * 2 + 1) * 512;
    const int offB  = w * 512;

    if (bid < 1024) {
        // ---------------- QK path: 128(m:bt) x 64(n:nh') ----------------
        const int m0 = (bid >> 5) << 7;       // 32 m-tiles
        const int n0 = (bid & 31) << 6;       // 32 n-tiles

        const bf16* pAh0 = Xh + (size_t)(m0 + jr0) * DD + kch;
        const bf16* pAh1 = Xh + (size_t)(m0 + jr1) * DD + kch;
        const bf16* pAl0 = Xl + (size_t)(m0 + jr0) * DD + kch;
        const bf16* pAl1 = Xl + (size_t)(m0 + jr1) * DD + kch;
        const bf16* pBh  = Wh + (size_t)(n0 + jrB) * DD + kch;
        const bf16* pBl  = Wl + (size_t)(n0 + jrB) * DD + kch;

        f32x4 acc[4][2] = {};

        for (int k0 = 0; k0 < DD; k0 += 32) {
            __syncthreads();
            gld16(pAh0 + k0, SA[0] + offA0);  gld16(pAh1 + k0, SA[0] + offA1);
            gld16(pAl0 + k0, SA[1] + offA0);  gld16(pAl1 + k0, SA[1] + offA1);
            gld16(pBh  + k0, SB[0] + offB);
            gld16(pBl  + k0, SB[1] + offB);
            __syncthreads();

            bf16x8 ah[4], bh[2];
            #pragma unroll
            for (int mt = 0; mt < 4; ++mt)
                ah[mt] = *(const bf16x8*)(SA[0] + (wm + (mt << 4) + l15) * 32 + (quad << 3));
            #pragma unroll
            for (int nt = 0; nt < 2; ++nt)
                bh[nt] = *(const bf16x8*)(SB[0] + (wn + (nt << 4) + l15) * 32 + (quad << 3));
            #pragma unroll
            for (int mt = 0; mt < 4; ++mt)
                #pragma unroll
                for (int nt = 0; nt < 2; ++nt)
                    acc[mt][nt] = __builtin_amdgcn_mfma_f32_16x16x32_bf16(
                        ah[mt], bh[nt], acc[mt][nt], 0, 0, 0);

            bf16x8 bl[2];
            #pragma unroll
            for (int nt = 0; nt < 2; ++nt)
                bl[nt] = *(const bf16x8*)(SB[1] + (wn + (nt << 4) + l15) * 32 + (quad << 3));
            #pragma unroll
            for (int mt = 0; mt < 4; ++mt)
                #pragma unroll
                for (int nt = 0; nt < 2; ++nt)
                    acc[mt][nt] = __builtin_amdgcn_mfma_f32_16x16x32_bf16(
                        ah[mt], bl[nt], acc[mt][nt], 0, 0, 0);

            bf16x8 al[4];
            #pragma unroll
            for (int mt = 0; mt < 4; ++mt)
                al[mt] = *(const bf16x8*)(SA[1] + (wm + (mt << 4) + l15) * 32 + (quad << 3));
            #pragma unroll
            for (int mt = 0; mt < 4; ++mt)
                #pragma unroll
                for (int nt = 0; nt < 2; ++nt)
                    acc[mt][nt] = __builtin_amdgcn_mfma_f32_16x16x32_bf16(
                        al[mt], bh[nt], acc[mt][nt], 0, 0, 0);
        }

        #pragma unroll
        for (int nt = 0; nt < 2; ++nt) {
            const int col = n0 + wn + (nt << 4) + l15;
            const int isQ = (col < 1024);
            const int nh  = col & 1023;
            const int n   = nh >> 6, h = nh & 63;
            const float bcol = isQ ? bq[nh] : bk[nh];
            float s = 1.f;
            if (isQ) {
                float x  = pds[h];
                float sp = fmaxf(x, 0.f) + log1pf(expf(-fabsf(x)));  // softplus
                s = (LOG2E_F * LOG2E_F / 8.0f) * sp;  // exp2 domain
            }
            bf16* dH = isQ ? oQh : oKh;
            bf16* dL = isQ ? oQl : oKl;
            #pragma unroll
            for (int mt = 0; mt < 4; ++mt) {
                #pragma unroll
                for (int reg = 0; reg < 4; ++reg) {
                    const int row = m0 + wm + (mt << 4) + (quad << 2) + reg;
                    const int bi  = row >> 11;
                    const int tt  = row & (TT - 1);
                    float val = (acc[mt][nt][reg] + bcol) * s;
                    const size_t idx = (((size_t)bi * NHD + n) * TT + tt) * HD + h;
                    bf16 hi = (bf16)val;
                    dH[idx] = hi;
                    dL[idx] = (bf16)(val - (float)hi);
                }
            }
        }
    } else {
        // ---------------- V path: 128(m:nh) x 64(n:bt) ----------------
        const int idx = bid - 1024;
        const int m0  = (idx >> 6) << 7;      // 8 nh tiles
        const int n0  = (idx & 63) << 6;      // 64 bt tiles

        const bf16* Ap0 = Wvh + (size_t)(m0 + jr0) * DD + kch;
        const bf16* Ap1 = Wvh + (size_t)(m0 + jr1) * DD + kch;
        const bf16* Bp  = Xh  + (size_t)(n0 + jrB) * DD + kch;

        f32x4 acc[4][2] = {};

        for (int k0 = 0; k0 < DD; k0 += 32) {
            __syncthreads();
            gld16(Ap0 + k0, SA[0] + offA0);
            gld16(Ap1 + k0, SA[0] + offA1);
            gld16(Bp  + k0, SB[0] + offB);
            __syncthreads();
            bf16x8 af[4], bfm[2];
            #pragma unroll
            for (int mt = 0; mt < 4; ++mt)
                af[mt] = *(const bf16x8*)(SA[0] + (wm + (mt << 4) + l15) * 32 + (quad << 3));
            #pragma unroll
            for (int nt = 0; nt < 2; ++nt)
                bfm[nt] = *(const bf16x8*)(SB[0] + (wn + (nt << 4) + l15) * 32 + (quad << 3));
            #pragma unroll
            for (int mt = 0; mt < 4; ++mt)
                #pragma unroll
                for (int nt = 0; nt < 2; ++nt)
                    acc[mt][nt] = __builtin_amdgcn_mfma_f32_16x16x32_bf16(
                        af[mt], bfm[nt], acc[mt][nt], 0, 0, 0);
        }

        #pragma unroll
        for (int nt = 0; nt < 2; ++nt) {
            const int col = n0 + wn + (nt << 4) + l15;   // bt
            const int bi  = col >> 11;
            const int tt  = col & (TT - 1);
            #pragma unroll
            for (int mt = 0; mt < 4; ++mt) {
                #pragma unroll
                for (int reg = 0; reg < 4; ++reg) {
                    const int row = m0 + wm + (mt << 4) + (quad << 2) + reg;  // nh
                    float val = acc[mt][nt][reg] + bv[row];
                    oVt[((size_t)bi * 1024 + row) * TT + tt] = (bf16)val;
                }
            }
        }
    }
}

// ---------------------------------------------------------------------------
// Output projection GEMM: 128x64 tile, 512 blocks (2/CU), BK=32, fp32 out.
// ---------------------------------------------------------------------------
__global__ __launch_bounds__(256)
void gemm_out(const bf16* __restrict__ A, const bf16* __restrict__ Bt,
              const float* __restrict__ bias, float* __restrict__ oF)
{
    __shared__ bf16 As[128 * 32];
    __shared__ bf16 Bs[64 * 32];

    const int t    = threadIdx.x;
    const int lane = t & 63;
    const int w    = t >> 6;
    const int quad = lane >> 4, l15 = lane & 15;
    const int m0   = blockIdx.y << 7;
    const int n0   = blockIdx.x << 6;
    const int wm   = (w >> 1) << 6;
    const int wn   = (w & 1)  << 5;

    const int jr0 = ((w * 2 + 0) << 4) + (lane >> 2);
    const int jr1 = ((w * 2 + 1) << 4) + (lane >> 2);
    const int jrB = (w << 4) + (lane >> 2);
    const int kch = (lane & 3) << 3;

    bf16* lA0 = As + (w * 2 + 0) * 512;
    bf16* lA1 = As + (w * 2 + 1) * 512;
    bf16* lB  = Bs + w * 512;

    const bf16* Ap0 = A  + (size_t)(m0 + jr0) * DD + kch;
    const bf16* Ap1 = A  + (size_t)(m0 + jr1) * DD + kch;
    const bf16* Bp  = Bt + (size_t)(n0 + jrB) * DD + kch;

    f32x4 acc[4][2] = {};

    for (int k0 = 0; k0 < DD; k0 += 32) {
        __syncthreads();
        gld16(Ap0 + k0, lA0);
        gld16(Ap1 + k0, lA1);
        gld16(Bp + k0, lB);
        __syncthreads();
        bf16x8 af[4], bfm[2];
        #pragma unroll
        for (int mt = 0; mt < 4; ++mt)
            af[mt] = *(const bf16x8*)(As + (wm + (mt << 4) + l15) * 32 + (quad << 3));
        #pragma unroll
        for (int nt = 0; nt < 2; ++nt)
            bfm[nt] = *(const bf16x8*)(Bs + (wn + (nt << 4) + l15) * 32 + (quad << 3));
        #pragma unroll
        for (int mt = 0; mt < 4; ++mt)
            #pragma unroll
            for (int nt = 0; nt < 2; ++nt)
                acc[mt][nt] = __builtin_amdgcn_mfma_f32_16x16x32_bf16(
                    af[mt], bfm[nt], acc[mt][nt], 0, 0, 0);
    }

    #pragma unroll
    for (int nt = 0; nt < 2; ++nt) {
        const int col = n0 + wn + (nt << 4) + l15;
        const float bcol = bias[col];
        #pragma unroll
        for (int mt = 0; mt < 4; ++mt) {
            #pragma unroll
            for (int reg = 0; reg < 4; ++reg) {
                const int row = m0 + wm + (mt << 4) + (quad << 2) + reg;
                oF[(size_t)row * DD + col] = acc[mt][nt][reg] + bcol;
            }
        }
    }
}

// ---------------------------------------------------------------------------
// MFMA flash attention (512 thr, q-tile 128, 8 waves), double-buffered,
// one barrier per iter (R6 structure, PASS @102us). Running max + defer-max
// (mandatory: sigma(S)~1500 exp2-domain). Mask folded into MFMA accumulator
// via lane-direct loads; row-sum via ones-row MFMA; swizzle (T2); setprio
// (T5). Prefetch addresses are running pointers (strength reduction).
// ---------------------------------------------------------------------------
__global__ __launch_bounds__(512, 4)
void attn_mfma(const bf16* __restrict__ Qh, const bf16* __restrict__ Ql,
               const bf16* __restrict__ Kh, const bf16* __restrict__ Kl,
               const bf16* __restrict__ Vt,
               const bf16* __restrict__ Madd,
               bf16* __restrict__ AO)
{
    __shared__ bf16 KH[2][64 * 64];
    __shared__ bf16 KL[2][64 * 64];
    __shared__ bf16 VS[2][64 * 64];    // [h][s], swizzled
    __shared__ bf16 PS[8][16 * 64];    // per-wave P, swizzled (same-wave RW)

    const int t    = threadIdx.x;
    const int lane = t & 63;
    const int w    = t >> 6;           // 0..7
    const int quad = lane >> 4, l15 = lane & 15;
    const int bn   = blockIdx.y;
    const int b    = bn >> 4, n = bn & 15;
    const int q0   = blockIdx.x << 7;  // 128 q per block

    const bf16* Qbh = Qh + (size_t)bn * TT * HD;
    const bf16* Qbl = Ql + (size_t)bn * TT * HD;
    const bf16* Kbh = Kh + (size_t)bn * TT * HD;
    const bf16* Kbl = Kl + (size_t)bn * TT * HD;
    const bf16* Vtb = Vt + (size_t)bn * HD * TT;
    const bf16* Mb  = Madd + (size_t)b * TT * TT;

    // Q fragments (B-operand: n=q=l15, k=h) — registers, loaded once
    const int qrow = q0 + (w << 4) + l15;
    bf16x8 qfh[2], qfl[2];
    qfh[0] = *(const bf16x8*)(Qbh + (size_t)qrow * HD + (quad << 3));
    qfh[1] = *(const bf16x8*)(Qbh + (size_t)qrow * HD + 32 + (quad << 3));
    qfl[0] = *(const bf16x8*)(Qbl + (size_t)qrow * HD + (quad << 3));
    qfl[1] = *(const bf16x8*)(Qbl + (size_t)qrow * HD + 32 + (quad << 3));

    f32x4 O[4];                         // O^T: row h=nt*16+quad*4+reg, col q=l15
    #pragma unroll
    for (int i = 0; i < 4; ++i) O[i] = (f32x4){0.f,0.f,0.f,0.f};
    f32x4 Ol = (f32x4){0.f,0.f,0.f,0.f};   // row-sum accumulator (ones-row)
    float m_i = -INFINITY;

    const bf16 onev = (bf16)1.0f;
    const bf16x8 ones = { onev, onev, onev, onev, onev, onev, onev, onev };

    // staging map: lane handles row rS, GLOBAL chunk (t&7); LDS write chunk
    // is XOR-swizzled so each 8-lane group fills one full 128B row.
    const int rS = t >> 3;                          // 0..63
    const int cG = (t & 7) << 3;                    // global elem offset
    const int cL = (((t & 7) ^ (rS & 7)) << 3);     // swizzled LDS offset
    // fragment-read swizzle key: row&7 == l15&7
    const int sw8 = (l15 & 7) << 3;

    // lane-direct mask base: this lane's q row, quad's 4-elem group
    const bf16* mrow0 = Mb + (size_t)qrow * TT + (quad << 2);

    // ---- prologue: stage tile 0 ----
    {
        bf16x8 khv = *(const bf16x8*)(Kbh + (size_t)rS * HD + cG);
        bf16x8 klv = *(const bf16x8*)(Kbl + (size_t)rS * HD + cG);
        bf16x8 vv  = *(const bf16x8*)(Vtb + (size_t)rS * TT + cG);
        *(bf16x8*)&KH[0][rS * 64 + cL] = khv;
        *(bf16x8*)&KL[0][rS * 64 + cL] = klv;
        *(bf16x8*)&VS[0][rS * 64 + cL] = vv;
    }
    ushort4 mu0 = *(const ushort4*)(mrow0);
    ushort4 mu1 = *(const ushort4*)(mrow0 + 16);
    ushort4 mu2 = *(const ushort4*)(mrow0 + 32);
    ushort4 mu3 = *(const ushort4*)(mrow0 + 48);
    __syncthreads();

    // running prefetch pointers (start at tile 1), constant strides per iter
    const bf16* kp = Kbh + (size_t)(64 + rS) * HD + cG;
    const bf16* lp = Kbl + (size_t)(64 + rS) * HD + cG;
    const bf16* vp = Vtb + (size_t)rS * TT + 64 + cG;
    const bf16* mp = mrow0 + 64;

    int cur = 0;
    for (int it = 0; it < 32; ++it) {
        const int last = (it == 31);
        // issue next tile's loads NOW — latency hides under this tile's work
        bf16x8 nkh, nkl, nvv;
        ushort4 nm0, nm1, nm2, nm3;
        if (!last) {
            nkh = *(const bf16x8*)(kp);
            nkl = *(const bf16x8*)(lp);
            nvv = *(const bf16x8*)(vp);
            nm0 = *(const ushort4*)(mp);
            nm1 = *(const ushort4*)(mp + 16);
            nm2 = *(const ushort4*)(mp + 32);
            nm3 = *(const ushort4*)(mp + 48);
            kp += 64 * HD; lp += 64 * HD; vp += 64; mp += 64;
        }

        const bf16* curKH = &KH[cur][0];
        const bf16* curKL = &KL[cur][0];
        const bf16* curVS = &VS[cur][0];

        // s_acc init = additive mask (C-in of the MFMA)
        f32x4 s_acc[4];
        s_acc[0][0] = __uint_as_float((unsigned)mu0.x << 16);
        s_acc[0][1] = __uint_as_float((unsigned)mu0.y << 16);
        s_acc[0][2] = __uint_as_float((unsigned)mu0.z << 16);
        s_acc[0][3] = __uint_as_float((unsigned)mu0.w << 16);
        s_acc[1][0] = __uint_as_float((unsigned)mu1.x << 16);
        s_acc[1][1] = __uint_as_float((unsigned)mu1.y << 16);
        s_acc[1][2] = __uint_as_float((unsigned)mu1.z << 16);
        s_acc[1][3] = __uint_as_float((unsigned)mu1.w << 16);
        s_acc[2][0] = __uint_as_float((unsigned)mu2.x << 16);
        s_acc[2][1] = __uint_as_float((unsigned)mu2.y << 16);
        s_acc[2][2] = __uint_as_float((unsigned)mu2.z << 16);
        s_acc[2][3] = __uint_as_float((unsigned)mu2.w << 16);
        s_acc[3][0] = __uint_as_float((unsigned)mu3.x << 16);
        s_acc[3][1] = __uint_as_float((unsigned)mu3.y << 16);
        s_acc[3][2] = __uint_as_float((unsigned)mu3.z << 16);
        s_acc[3][3] = __uint_as_float((unsigned)mu3.w << 16);

        // S^T = K Q^T + M (rows s, cols q), split: Kh*Qh + Kl*Qh + Kh*Ql
        __builtin_amdgcn_s_setprio(1);
        #pragma unroll
        for (int k2 = 0; k2 < 2; ++k2) {
            #pragma unroll
            for (int nt = 0; nt < 4; ++nt) {
                const int ro = ((nt << 4) + l15) * 64;
                const int co = ((k2 << 5) + (quad << 3)) ^ sw8;
                bf16x8 bkh = *(const bf16x8*)&curKH[ro + co];
                bf16x8 bkl = *(const bf16x8*)&curKL[ro + co];
                s_acc[nt] = __builtin_amdgcn_mfma_f32_16x16x32_bf16(bkh, qfh[k2], s_acc[nt], 0, 0, 0);
                s_acc[nt] = __builtin_amdgcn_mfma_f32_16x16x32_bf16(bkl, qfh[k2], s_acc[nt], 0, 0, 0);
                s_acc[nt] = __builtin_amdgcn_mfma_f32_16x16x32_bf16(bkh, qfl[k2], s_acc[nt], 0, 0, 0);
            }
        }
        __builtin_amdgcn_s_setprio(0);

        // per-lane softmax over s — mask already inside s_acc.
        float t0 = fmaxf(fmaxf(s_acc[0][0], s_acc[0][1]), s_acc[0][2]);
        float t1 = fmaxf(fmaxf(s_acc[0][3], s_acc[1][0]), s_acc[1][1]);
        float t2 = fmaxf(fmaxf(s_acc[1][2], s_acc[1][3]), s_acc[2][0]);
        float t3 = fmaxf(fmaxf(s_acc[2][1], s_acc[2][2]), s_acc[2][3]);
        float t4 = fmaxf(fmaxf(s_acc[3][0], s_acc[3][1]), s_acc[3][2]);
        float mx = fmaxf(fmaxf(fmaxf(t0, t1), t2),
                         fmaxf(fmaxf(t3, t4), s_acc[3][3]));
        mx = fmaxf(mx, __shfl_xor(mx, 16));
        mx = fmaxf(mx, __shfl_xor(mx, 32));

        // T13 defer-max (exp2 domain, THR=8); Ol rescales with O
        if (!__all(mx <= m_i + 8.0f)) {
            const float mnew  = fmaxf(m_i, mx);
            const float alpha = exp2f(m_i - mnew);   // exp2(-inf)=0 first tile
            #pragma unroll
            for (int nt = 0; nt < 4; ++nt) {
                O[nt][0] *= alpha; O[nt][1] *= alpha;
                O[nt][2] *= alpha; O[nt][3] *= alpha;
            }
            Ol[0] *= alpha; Ol[1] *= alpha; Ol[2] *= alpha; Ol[3] *= alpha;
            m_i = mnew;
        }

        float p[16];
        #pragma unroll
        for (int nt = 0; nt < 4; ++nt)
            #pragma unroll
            for (int reg = 0; reg < 4; ++reg)
                p[nt * 4 + reg] = exp2f(s_acc[nt][reg] - m_i);  // masked -> 0

        #pragma unroll
        for (int nt = 0; nt < 4; ++nt) {
            bf16x4 pv = { (bf16)p[nt * 4 + 0], (bf16)p[nt * 4 + 1],
                          (bf16)p[nt * 4 + 2], (bf16)p[nt * 4 + 3] };
            *(bf16x4*)&PS[w][l15 * 64 + (((nt << 4) + (quad << 2)) ^ sw8)] = pv;
        }

        // O^T += Vt P^T  (A=Vt rows h, B=P rows q); ones-row MFMA -> row sums
        __builtin_amdgcn_s_setprio(1);
        #pragma unroll
        for (int s2i = 0; s2i < 2; ++s2i) {
            bf16x8 ap = *(const bf16x8*)&PS[w][l15 * 64 + (((s2i << 5) + (quad << 3)) ^ sw8)];
            Ol = __builtin_amdgcn_mfma_f32_16x16x32_bf16(ones, ap, Ol, 0, 0, 0);
            #pragma unroll
            for (int nt = 0; nt < 4; ++nt) {
                bf16x8 bv = *(const bf16x8*)&curVS[((nt << 4) + l15) * 64
                                                   + (((s2i << 5) + (quad << 3)) ^ sw8)];
                O[nt] = __builtin_amdgcn_mfma_f32_16x16x32_bf16(bv, ap, O[nt], 0, 0, 0);
            }
        }
        __builtin_amdgcn_s_setprio(0);

        // stage next tile into the other buffer; rotate mask regs
        if (!last) {
            const int nxt = cur ^ 1;
            *(bf16x8*)&KH[nxt][rS * 64 + cL] = nkh;
            *(bf16x8*)&KL[nxt][rS * 64 + cL] = nkl;
            *(bf16x8*)&VS[nxt][rS * 64 + cL] = nvv;
            mu0 = nm0; mu1 = nm1; mu2 = nm2; mu3 = nm3;
            __syncthreads();   // writes visible; all reads of buf[cur] done
            cur = nxt;
        }
    }

    // normalize + write AO (bf16, [B*T][N*H]); lane owns col q, rows h.
    // Ol regs all equal Σ_s p[s][q=l15] — every lane holds its own l.
    {
        const float inv = 1.0f / Ol[0];
        const size_t base = ((size_t)b * TT + qrow) * (NHD * HD) + (size_t)n * HD;
        #pragma unroll
        for (int nt = 0; nt < 4; ++nt) {
            bf16x4 o = { (bf16)(O[nt][0] * inv), (bf16)(O[nt][1] * inv),
                         (bf16)(O[nt][2] * inv), (bf16)(O[nt][3] * inv) };
            *(bf16x4*)(AO + base + (nt << 4) + (quad << 2)) = o;
        }
    }
}

// ---------------------------------------------------------------------------
extern "C" void kernel_launch(void* const* d_in, const int* in_sizes, int n_in,
                              void* d_out, int out_size, void* d_ws, size_t ws_size,
                              hipStream_t stream)
{
    const float* X   = (const float*)d_in[0];
    const int*   msk = (const int*)d_in[1];
    const float* wq  = (const float*)d_in[2];
    const float* bq  = (const float*)d_in[3];
    const float* wk  = (const float*)d_in[4];
    const float* bk  = (const float*)d_in[5];
    const float* wv  = (const float*)d_in[6];
    const float* bv  = (const float*)d_in[7];
    const float* wo  = (const float*)d_in[8];
    const float* bo  = (const float*)d_in[9];
    const float* pds = (const float*)d_in[10];
    float* out = (float*)d_out;

    bf16* ws   = (bf16*)d_ws;
    bf16* Xh   = ws;                      // 4M  (later aliased by AO)
    bf16* Xl   = ws + 4194304;            // 4M
    bf16* WQKh = ws + 8388608;            // 2M  [2048 nh'][1024 d]
    bf16* WQKl = ws + 10485760;           // 2M
    bf16* Wvh  = ws + 12582912;           // 1M  [nh][d]
    bf16* Wob  = ws + 13631488;           // 1M  [d][nh]
    bf16* Qhb  = ws + 14680064;           // 4M  [b][n][t][h]
    bf16* Qlb  = ws + 18874368;
    bf16* Khb  = ws + 23068672;
    bf16* Klb  = ws + 27262976;
    bf16* Vtb  = ws + 32505856;           // 4M [b][nh][t]
    bf16* AOb  = Xh;                      // alias: Xh dead after proj
    // additive mask lives in d_out (16 MB = out_size exactly); it is consumed
    // by attn_mfma BEFORE gemm_out overwrites d_out with the final result.
    bf16* madd = (bf16*)d_out;

    dim3 blk(256);

    prep_all<<<12288, blk, 0, stream>>>(X, msk, wq, wk, wv, wo,
                                        Xh, Xl, WQKh, WQKl, Wvh, Wob, madd);

    // fused QK + V projections (retiled: 1024 QK blocks + 512 V blocks)
    gemm_proj<<<1536, blk, 0, stream>>>(
        Xh, Xl, WQKh, WQKl, Wvh, bq, bk, bv, pds,
        Qhb, Qlb, Khb, Klb, Vtb);

    dim3 ga(TT / 128, BB * NHD);   // (16, 32)
    attn_mfma<<<ga, dim3(512), 0, stream>>>(
        Qhb, Qlb, Khb, Klb, Vtb, madd, AOb);

    // output projection: M=4096, N=1024, K=1024, fp32 out, 128x64 tiles
    gemm_out<<<dim3(16, 32), blk, 0, stream>>>(AOb, Wob, bo, out);
}

// Round 10
// 306.071 us; speedup vs baseline: 1.0164x; 1.0164x over previous
//
#include <hip/hip_runtime.h>
#include <math.h>

typedef __bf16 bf16;
typedef __attribute__((ext_vector_type(8))) __bf16 bf16x8;
typedef __attribute__((ext_vector_type(4))) __bf16 bf16x4;
typedef __attribute__((ext_vector_type(4))) float f32x4;

#define BB 2
#define TT 2048
#define DD 1024
#define NHD 16
#define HD 64
#define MM (BB*TT)          // 4096
#define LOG2E_F 1.442695041f
#define NEGINF_F (-1.0e9f)

// async global->LDS, 16B per lane; LDS dest must be wave-uniform base
__device__ __forceinline__ void gld16(const bf16* g, bf16* l)
{
    __builtin_amdgcn_global_load_lds(
        (const __attribute__((address_space(1))) unsigned int*)g,
        (__attribute__((address_space(3))) unsigned int*)l, 16, 0, 0);
}

// ---------------------------------------------------------------------------
// fused prep (8192 blocks): [0,4096) split_x; [4096,8192) weight
// transpose/convert. Mask conversion moved into gemm_proj tail blocks (R10)
// since gemm_proj does not consume the mask — overlap instead of serialize.
// NOTE (R7 lesson): sigma(S) ~ 1500 in exp2 domain -> running max mandatory.
// ---------------------------------------------------------------------------
__global__ __launch_bounds__(256)
void prep_all(const float* __restrict__ X,
              const float* __restrict__ wq, const float* __restrict__ wk,
              const float* __restrict__ wv, const float* __restrict__ wo,
              bf16* __restrict__ Xh, bf16* __restrict__ Xl,
              bf16* __restrict__ qkh, bf16* __restrict__ qkl,
              bf16* __restrict__ vh, bf16* __restrict__ ob)
{
    __shared__ float tile[32][33];
    const int bid = blockIdx.x;
    const int t   = threadIdx.x;

    if (bid < 4096) {                         // split X -> hi/lo
        int i = bid * 256 + t;
        float4 v = ((const float4*)X)[i];
        float f[4] = {v.x, v.y, v.z, v.w};
        bf16x4 h, l;
        #pragma unroll
        for (int j = 0; j < 4; ++j) {
            bf16 hh = (bf16)f[j];
            h[j] = hh;
            l[j] = (bf16)(f[j] - (float)hh);
        }
        *(bf16x4*)(Xh + (size_t)i * 4) = h;
        *(bf16x4*)(Xl + (size_t)i * 4) = l;
        return;
    }
    {                                         // weights
        const int idx = bid - 4096;
        const int z   = idx >> 10;            // 0:wq 1:wk 2:wv 3:wo
        const int bx  = (idx & 31) << 5;      // nh block
        const int by  = ((idx >> 5) & 31) << 5;  // d block
        const int r   = t >> 3;
        const int c4  = (t & 7) << 2;
        if (z == 3) {
            float4 v = *(const float4*)(wo + (size_t)(by + r) * 1024 + bx + c4);
            bf16x4 o = { (bf16)v.x, (bf16)v.y, (bf16)v.z, (bf16)v.w };
            *(bf16x4*)(ob + (size_t)(by + r) * 1024 + bx + c4) = o;
            return;
        }
        const float* src = (z == 0) ? wq : ((z == 1) ? wk : wv);
        bf16* oh = (z == 0) ? qkh : ((z == 1) ? qkh + 1048576 : vh);
        bf16* ol = (z == 0) ? qkl : ((z == 1) ? qkl + 1048576 : nullptr);
        float4 v = *(const float4*)(src + (size_t)(by + r) * 1024 + bx + c4);
        tile[r][c4+0] = v.x; tile[r][c4+1] = v.y;
        tile[r][c4+2] = v.z; tile[r][c4+3] = v.w;
        __syncthreads();
        bf16x4 hv, lv;
        #pragma unroll
        for (int j = 0; j < 4; ++j) {
            float f = tile[c4 + j][r];
            bf16 h = (bf16)f;
            hv[j] = h;
            lv[j] = (bf16)(f - (float)h);
        }
        *(bf16x4*)(oh + (size_t)(bx + r) * 1024 + by + c4) = hv;
        if (ol)
            *(bf16x4*)(ol + (size_t)(bx + r) * 1024 + by + c4) = lv;
    }
}

// ---------------------------------------------------------------------------
// Fused projection GEMM + mask conversion (5632 blocks):
//  [0,1024): QK — 3-pass split (Xh*Wh + Xh*Wl + Xl*Wh), 128(bt)x64(nh'),
//            BK=32; col<1024 -> Q (scaled, exp2-domain), else K; hi/lo out.
//  [1024,1536): V — C^T = Wvh · Xh^T, 128(nh)x64(bt), out Vt + bias.
//  [1536,5632): mask -> additive bf16 (0 / -1e9) into d_out — tail-fill:
//            pure-BW blocks overlap the GEMM tail & latency bubbles; the
//            mask is consumed only by attn (launched after this kernel).
// XCD-swizzled (T1) within GEMM segments.
// ---------------------------------------------------------------------------
__global__ __launch_bounds__(256)
void gemm_proj(const bf16* __restrict__ Xh, const bf16* __restrict__ Xl,
               const bf16* __restrict__ Wh, const bf16* __restrict__ Wl,
               const bf16* __restrict__ Wvh,
               const float* __restrict__ bq, const float* __restrict__ bk,
               const float* __restrict__ bv, const float* __restrict__ pds,
               const int* __restrict__ m,
               bf16* __restrict__ oQh, bf16* __restrict__ oQl,
               bf16* __restrict__ oKh, bf16* __restrict__ oKl,
               bf16* __restrict__ oVt, bf16* __restrict__ madd)
{
    __shared__ bf16 SA[2][128 * 32];   // A hi/lo: 16 KB
    __shared__ bf16 SB[2][64 * 32];    // B hi/lo:  8 KB

    int bid = blockIdx.x;
    const int t = threadIdx.x;

    if (bid >= 1536) {                 // ---- fused mask conversion ----
        int i = (bid - 1536) * 256 + t;       // i < 1048576 (8 elems each)
        const int4* mp = (const int4*)m + (size_t)i * 2;
        int4 a  = mp[0];
        int4 b4 = mp[1];
        bf16x8 o;
        o[0] = (bf16)(a.x  ? 0.f : NEGINF_F);
        o[1] = (bf16)(a.y  ? 0.f : NEGINF_F);
        o[2] = (bf16)(a.z  ? 0.f : NEGINF_F);
        o[3] = (bf16)(a.w  ? 0.f : NEGINF_F);
        o[4] = (bf16)(b4.x ? 0.f : NEGINF_F);
        o[5] = (bf16)(b4.y ? 0.f : NEGINF_F);
        o[6] = (bf16)(b4.z ? 0.f : NEGINF_F);
        o[7] = (bf16)(b4.w ? 0.f : NEGINF_F);
        *(bf16x8*)(madd + (size_t)i * 8) = o;
        return;
    }

    // bijective XCD swizzle within each GEMM segment (8 XCDs)
    if (bid < 1024) bid = ((bid & 7) << 7) + (bid >> 3);
    else {
        int idx = bid - 1024;
        bid = 1024 + (((idx & 7) << 6) + (idx >> 3));
    }

    const int lane = t & 63;
    const int w    = t >> 6;
    const int quad = lane >> 4, l15 = lane & 15;
    const int wm   = (w >> 1) << 6;    // 0 / 64
    const int wn   = (w & 1)  << 5;    // 0 / 32

    const int jr0 = ((w * 2 + 0) << 4) + (lane >> 2);   // A rows, site 0
    const int jr1 = ((w * 2 + 1) << 4) + (lane >> 2);   // A rows, site 1
    const int jrB = (w << 4) + (lane >> 2);             // B rows (64)
    const int kch = (lane & 3) << 3;
    const int offA0 = (w * 2 + 0) * 512;
    const int offA1 = (w * 2 + 1) * 512;
    const int offB  = w * 512;

    if (bid < 1024) {
        // ---------------- QK path: 128(m:bt) x 64(n:nh') ----------------
        const int m0 = (bid >> 5) << 7;       // 32 m-tiles
        const int n0 = (bid & 31) << 6;       // 32 n-tiles

        const bf16* pAh0 = Xh + (size_t)(m0 + jr0) * DD + kch;
        const bf16* pAh1 = Xh + (size_t)(m0 + jr1) * DD + kch;
        const bf16* pAl0 = Xl + (size_t)(m0 + jr0) * DD + kch;
        const bf16* pAl1 = Xl + (size_t)(m0 + jr1) * DD + kch;
        const bf16* pBh  = Wh + (size_t)(n0 + jrB) * DD + kch;
        const bf16* pBl  = Wl + (size_t)(n0 + jrB) * DD + kch;

        f32x4 acc[4][2] = {};

        for (int k0 = 0; k0 < DD; k0 += 32) {
            __syncthreads();
            gld16(pAh0 + k0, SA[0] + offA0);  gld16(pAh1 + k0, SA[0] + offA1);
            gld16(pAl0 + k0, SA[1] + offA0);  gld16(pAl1 + k0, SA[1] + offA1);
            gld16(pBh  + k0, SB[0] + offB);
            gld16(pBl  + k0, SB[1] + offB);
            __syncthreads();

            bf16x8 ah[4], bh[2];
            #pragma unroll
            for (int mt = 0; mt < 4; ++mt)
                ah[mt] = *(const bf16x8*)(SA[0] + (wm + (mt << 4) + l15) * 32 + (quad << 3));
            #pragma unroll
            for (int nt = 0; nt < 2; ++nt)
                bh[nt] = *(const bf16x8*)(SB[0] + (wn + (nt << 4) + l15) * 32 + (quad << 3));
            #pragma unroll
            for (int mt = 0; mt < 4; ++mt)
                #pragma unroll
                for (int nt = 0; nt < 2; ++nt)
                    acc[mt][nt] = __builtin_amdgcn_mfma_f32_16x16x32_bf16(
                        ah[mt], bh[nt], acc[mt][nt], 0, 0, 0);

            bf16x8 bl[2];
            #pragma unroll
            for (int nt = 0; nt < 2; ++nt)
                bl[nt] = *(const bf16x8*)(SB[1] + (wn + (nt << 4) + l15) * 32 + (quad << 3));
            #pragma unroll
            for (int mt = 0; mt < 4; ++mt)
                #pragma unroll
                for (int nt = 0; nt < 2; ++nt)
                    acc[mt][nt] = __builtin_amdgcn_mfma_f32_16x16x32_bf16(
                        ah[mt], bl[nt], acc[mt][nt], 0, 0, 0);

            bf16x8 al[4];
            #pragma unroll
            for (int mt = 0; mt < 4; ++mt)
                al[mt] = *(const bf16x8*)(SA[1] + (wm + (mt << 4) + l15) * 32 + (quad << 3));
            #pragma unroll
            for (int mt = 0; mt < 4; ++mt)
                #pragma unroll
                for (int nt = 0; nt < 2; ++nt)
                    acc[mt][nt] = __builtin_amdgcn_mfma_f32_16x16x32_bf16(
                        al[mt], bh[nt], acc[mt][nt], 0, 0, 0);
        }

        #pragma unroll
        for (int nt = 0; nt < 2; ++nt) {
            const int col = n0 + wn + (nt << 4) + l15;
            const int isQ = (col < 1024);
            const int nh  = col & 1023;
            const int n   = nh >> 6, h = nh & 63;
            const float bcol = isQ ? bq[nh] : bk[nh];
            float s = 1.f;
            if (isQ) {
                float x  = pds[h];
                float sp = fmaxf(x, 0.f) + log1pf(expf(-fabsf(x)));  // softplus
                s = (LOG2E_F * LOG2E_F / 8.0f) * sp;  // exp2 domain
            }
            bf16* dH = isQ ? oQh : oKh;
            bf16* dL = isQ ? oQl : oKl;
            #pragma unroll
            for (int mt = 0; mt < 4; ++mt) {
                #pragma unroll
                for (int reg = 0; reg < 4; ++reg) {
                    const int row = m0 + wm + (mt << 4) + (quad << 2) + reg;
                    const int bi  = row >> 11;
                    const int tt  = row & (TT - 1);
                    float val = (acc[mt][nt][reg] + bcol) * s;
                    const size_t idx = (((size_t)bi * NHD + n) * TT + tt) * HD + h;
                    bf16 hi = (bf16)val;
                    dH[idx] = hi;
                    dL[idx] = (bf16)(val - (float)hi);
                }
            }
        }
    } else {
        // ---------------- V path: 128(m:nh) x 64(n:bt) ----------------
        const int idx = bid - 1024;
        const int m0  = (idx >> 6) << 7;      // 8 nh tiles
        const int n0  = (idx & 63) << 6;      // 64 bt tiles

        const bf16* Ap0 = Wvh + (size_t)(m0 + jr0) * DD + kch;
        const bf16* Ap1 = Wvh + (size_t)(m0 + jr1) * DD + kch;
        const bf16* Bp  = Xh  + (size_t)(n0 + jrB) * DD + kch;

        f32x4 acc[4][2] = {};

        for (int k0 = 0; k0 < DD; k0 += 32) {
            __syncthreads();
            gld16(Ap0 + k0, SA[0] + offA0);
            gld16(Ap1 + k0, SA[0] + offA1);
            gld16(Bp  + k0, SB[0] + offB);
            __syncthreads();
            bf16x8 af[4], bfm[2];
            #pragma unroll
            for (int mt = 0; mt < 4; ++mt)
                af[mt] = *(const bf16x8*)(SA[0] + (wm + (mt << 4) + l15) * 32 + (quad << 3));
            #pragma unroll
            for (int nt = 0; nt < 2; ++nt)
                bfm[nt] = *(const bf16x8*)(SB[0] + (wn + (nt << 4) + l15) * 32 + (quad << 3));
            #pragma unroll
            for (int mt = 0; mt < 4; ++mt)
                #pragma unroll
                for (int nt = 0; nt < 2; ++nt)
                    acc[mt][nt] = __builtin_amdgcn_mfma_f32_16x16x32_bf16(
                        af[mt], bfm[nt], acc[mt][nt], 0, 0, 0);
        }

        #pragma unroll
        for (int nt = 0; nt < 2; ++nt) {
            const int col = n0 + wn + (nt << 4) + l15;   // bt
            const int bi  = col >> 11;
            const int tt  = col & (TT - 1);
            #pragma unroll
            for (int mt = 0; mt < 4; ++mt) {
                #pragma unroll
                for (int reg = 0; reg < 4; ++reg) {
                    const int row = m0 + wm + (mt << 4) + (quad << 2) + reg;  // nh
                    float val = acc[mt][nt][reg] + bv[row];
                    oVt[((size_t)bi * 1024 + row) * TT + tt] = (bf16)val;
                }
            }
        }
    }
}

// ---------------------------------------------------------------------------
// Output projection GEMM: 128x64 tile, 512 blocks (2/CU), BK=32, fp32 out.
// ---------------------------------------------------------------------------
__global__ __launch_bounds__(256)
void gemm_out(const bf16* __restrict__ A, const bf16* __restrict__ Bt,
              const float* __restrict__ bias, float* __restrict__ oF)
{
    __shared__ bf16 As[128 * 32];
    __shared__ bf16 Bs[64 * 32];

    const int t    = threadIdx.x;
    const int lane = t & 63;
    const int w    = t >> 6;
    const int quad = lane >> 4, l15 = lane & 15;
    const int m0   = blockIdx.y << 7;
    const int n0   = blockIdx.x << 6;
    const int wm   = (w >> 1) << 6;
    const int wn   = (w & 1)  << 5;

    const int jr0 = ((w * 2 + 0) << 4) + (lane >> 2);
    const int jr1 = ((w * 2 + 1) << 4) + (lane >> 2);
    const int jrB = (w << 4) + (lane >> 2);
    const int kch = (lane & 3) << 3;

    bf16* lA0 = As + (w * 2 + 0) * 512;
    bf16* lA1 = As + (w * 2 + 1) * 512;
    bf16* lB  = Bs + w * 512;

    const bf16* Ap0 = A  + (size_t)(m0 + jr0) * DD + kch;
    const bf16* Ap1 = A  + (size_t)(m0 + jr1) * DD + kch;
    const bf16* Bp  = Bt + (size_t)(n0 + jrB) * DD + kch;

    f32x4 acc[4][2] = {};

    for (int k0 = 0; k0 < DD; k0 += 32) {
        __syncthreads();
        gld16(Ap0 + k0, lA0);
        gld16(Ap1 + k0, lA1);
        gld16(Bp + k0, lB);
        __syncthreads();
        bf16x8 af[4], bfm[2];
        #pragma unroll
        for (int mt = 0; mt < 4; ++mt)
            af[mt] = *(const bf16x8*)(As + (wm + (mt << 4) + l15) * 32 + (quad << 3));
        #pragma unroll
        for (int nt = 0; nt < 2; ++nt)
            bfm[nt] = *(const bf16x8*)(Bs + (wn + (nt << 4) + l15) * 32 + (quad << 3));
        #pragma unroll
        for (int mt = 0; mt < 4; ++mt)
            #pragma unroll
            for (int nt = 0; nt < 2; ++nt)
                acc[mt][nt] = __builtin_amdgcn_mfma_f32_16x16x32_bf16(
                    af[mt], bfm[nt], acc[mt][nt], 0, 0, 0);
    }

    #pragma unroll
    for (int nt = 0; nt < 2; ++nt) {
        const int col = n0 + wn + (nt << 4) + l15;
        const float bcol = bias[col];
        #pragma unroll
        for (int mt = 0; mt < 4; ++mt) {
            #pragma unroll
            for (int reg = 0; reg < 4; ++reg) {
                const int row = m0 + wm + (mt << 4) + (quad << 2) + reg;
                oF[(size_t)row * DD + col] = acc[mt][nt][reg] + bcol;
            }
        }
    }
}

// ---------------------------------------------------------------------------
// MFMA flash attention (512 thr, q-tile 128, 8 waves), double-buffered,
// one barrier per iter (R6 structure, PASS @102us). Running max + defer-max
// (mandatory: sigma(S)~1500 exp2-domain). Mask folded into MFMA accumulator
// via lane-direct loads; row-sum via ones-row MFMA; swizzle (T2); setprio
// (T5). Prefetch addresses are running pointers (strength reduction).
// ---------------------------------------------------------------------------
__global__ __launch_bounds__(512, 4)
void attn_mfma(const bf16* __restrict__ Qh, const bf16* __restrict__ Ql,
               const bf16* __restrict__ Kh, const bf16* __restrict__ Kl,
               const bf16* __restrict__ Vt,
               const bf16* __restrict__ Madd,
               bf16* __restrict__ AO)
{
    __shared__ bf16 KH[2][64 * 64];
    __shared__ bf16 KL[2][64 * 64];
    __shared__ bf16 VS[2][64 * 64];    // [h][s], swizzled
    __shared__ bf16 PS[8][16 * 64];    // per-wave P, swizzled (same-wave RW)

    const int t    = threadIdx.x;
    const int lane = t & 63;
    const int w    = t >> 6;           // 0..7
    const int quad = lane >> 4, l15 = lane & 15;
    const int bn   = blockIdx.y;
    const int b    = bn >> 4, n = bn & 15;
    const int q0   = blockIdx.x << 7;  // 128 q per block

    const bf16* Qbh = Qh + (size_t)bn * TT * HD;
    const bf16* Qbl = Ql + (size_t)bn * TT * HD;
    const bf16* Kbh = Kh + (size_t)bn * TT * HD;
    const bf16* Kbl = Kl + (size_t)bn * TT * HD;
    const bf16* Vtb = Vt + (size_t)bn * HD * TT;
    const bf16* Mb  = Madd + (size_t)b * TT * TT;

    // Q fragments (B-operand: n=q=l15, k=h) — registers, loaded once
    const int qrow = q0 + (w << 4) + l15;
    bf16x8 qfh[2], qfl[2];
    qfh[0] = *(const bf16x8*)(Qbh + (size_t)qrow * HD + (quad << 3));
    qfh[1] = *(const bf16x8*)(Qbh + (size_t)qrow * HD + 32 + (quad << 3));
    qfl[0] = *(const bf16x8*)(Qbl + (size_t)qrow * HD + (quad << 3));
    qfl[1] = *(const bf16x8*)(Qbl + (size_t)qrow * HD + 32 + (quad << 3));

    f32x4 O[4];                         // O^T: row h=nt*16+quad*4+reg, col q=l15
    #pragma unroll
    for (int i = 0; i < 4; ++i) O[i] = (f32x4){0.f,0.f,0.f,0.f};
    f32x4 Ol = (f32x4){0.f,0.f,0.f,0.f};   // row-sum accumulator (ones-row)
    float m_i = -INFINITY;

    const bf16 onev = (bf16)1.0f;
    const bf16x8 ones = { onev, onev, onev, onev, onev, onev, onev, onev };

    // staging map: lane handles row rS, GLOBAL chunk (t&7); LDS write chunk
    // is XOR-swizzled so each 8-lane group fills one full 128B row.
    const int rS = t >> 3;                          // 0..63
    const int cG = (t & 7) << 3;                    // global elem offset
    const int cL = (((t & 7) ^ (rS & 7)) << 3);     // swizzled LDS offset
    // fragment-read swizzle key: row&7 == l15&7
    const int sw8 = (l15 & 7) << 3;

    // lane-direct mask base: this lane's q row, quad's 4-elem group
    const bf16* mrow0 = Mb + (size_t)qrow * TT + (quad << 2);

    // ---- prologue: stage tile 0 ----
    {
        bf16x8 khv = *(const bf16x8*)(Kbh + (size_t)rS * HD + cG);
        bf16x8 klv = *(const bf16x8*)(Kbl + (size_t)rS * HD + cG);
        bf16x8 vv  = *(const bf16x8*)(Vtb + (size_t)rS * TT + cG);
        *(bf16x8*)&KH[0][rS * 64 + cL] = khv;
        *(bf16x8*)&KL[0][rS * 64 + cL] = klv;
        *(bf16x8*)&VS[0][rS * 64 + cL] = vv;
    }
    ushort4 mu0 = *(const ushort4*)(mrow0);
    ushort4 mu1 = *(const ushort4*)(mrow0 + 16);
    ushort4 mu2 = *(const ushort4*)(mrow0 + 32);
    ushort4 mu3 = *(const ushort4*)(mrow0 + 48);
    __syncthreads();

    // running prefetch pointers (start at tile 1), constant strides per iter
    const bf16* kp = Kbh + (size_t)(64 + rS) * HD + cG;
    const bf16* lp = Kbl + (size_t)(64 + rS) * HD + cG;
    const bf16* vp = Vtb + (size_t)rS * TT + 64 + cG;
    const bf16* mp = mrow0 + 64;

    int cur = 0;
    for (int it = 0; it < 32; ++it) {
        const int last = (it == 31);
        // issue next tile's loads NOW — latency hides under this tile's work
        bf16x8 nkh, nkl, nvv;
        ushort4 nm0, nm1, nm2, nm3;
        if (!last) {
            nkh = *(const bf16x8*)(kp);
            nkl = *(const bf16x8*)(lp);
            nvv = *(const bf16x8*)(vp);
            nm0 = *(const ushort4*)(mp);
            nm1 = *(const ushort4*)(mp + 16);
            nm2 = *(const ushort4*)(mp + 32);
            nm3 = *(const ushort4*)(mp + 48);
            kp += 64 * HD; lp += 64 * HD; vp += 64; mp += 64;
        }

        const bf16* curKH = &KH[cur][0];
        const bf16* curKL = &KL[cur][0];
        const bf16* curVS = &VS[cur][0];

        // s_acc init = additive mask (C-in of the MFMA)
        f32x4 s_acc[4];
        s_acc[0][0] = __uint_as_float((unsigned)mu0.x << 16);
        s_acc[0][1] = __uint_as_float((unsigned)mu0.y << 16);
        s_acc[0][2] = __uint_as_float((unsigned)mu0.z << 16);
        s_acc[0][3] = __uint_as_float((unsigned)mu0.w << 16);
        s_acc[1][0] = __uint_as_float((unsigned)mu1.x << 16);
        s_acc[1][1] = __uint_as_float((unsigned)mu1.y << 16);
        s_acc[1][2] = __uint_as_float((unsigned)mu1.z << 16);
        s_acc[1][3] = __uint_as_float((unsigned)mu1.w << 16);
        s_acc[2][0] = __uint_as_float((unsigned)mu2.x << 16);
        s_acc[2][1] = __uint_as_float((unsigned)mu2.y << 16);
        s_acc[2][2] = __uint_as_float((unsigned)mu2.z << 16);
        s_acc[2][3] = __uint_as_float((unsigned)mu2.w << 16);
        s_acc[3][0] = __uint_as_float((unsigned)mu3.x << 16);
        s_acc[3][1] = __uint_as_float((unsigned)mu3.y << 16);
        s_acc[3][2] = __uint_as_float((unsigned)mu3.z << 16);
        s_acc[3][3] = __uint_as_float((unsigned)mu3.w << 16);

        // S^T = K Q^T + M (rows s, cols q), split: Kh*Qh + Kl*Qh + Kh*Ql
        __builtin_amdgcn_s_setprio(1);
        #pragma unroll
        for (int k2 = 0; k2 < 2; ++k2) {
            #pragma unroll
            for (int nt = 0; nt < 4; ++nt) {
                const int ro = ((nt << 4) + l15) * 64;
                const int co = ((k2 << 5) + (quad << 3)) ^ sw8;
                bf16x8 bkh = *(const bf16x8*)&curKH[ro + co];
                bf16x8 bkl = *(const bf16x8*)&curKL[ro + co];
                s_acc[nt] = __builtin_amdgcn_mfma_f32_16x16x32_bf16(bkh, qfh[k2], s_acc[nt], 0, 0, 0);
                s_acc[nt] = __builtin_amdgcn_mfma_f32_16x16x32_bf16(bkl, qfh[k2], s_acc[nt], 0, 0, 0);
                s_acc[nt] = __builtin_amdgcn_mfma_f32_16x16x32_bf16(bkh, qfl[k2], s_acc[nt], 0, 0, 0);
            }
        }
        __builtin_amdgcn_s_setprio(0);

        // per-lane softmax over s — mask already inside s_acc.
        float t0 = fmaxf(fmaxf(s_acc[0][0], s_acc[0][1]), s_acc[0][2]);
        float t1 = fmaxf(fmaxf(s_acc[0][3], s_acc[1][0]), s_acc[1][1]);
        float t2 = fmaxf(fmaxf(s_acc[1][2], s_acc[1][3]), s_acc[2][0]);
        float t3 = fmaxf(fmaxf(s_acc[2][1], s_acc[2][2]), s_acc[2][3]);
        float t4 = fmaxf(fmaxf(s_acc[3][0], s_acc[3][1]), s_acc[3][2]);
        float mx = fmaxf(fmaxf(fmaxf(t0, t1), t2),
                         fmaxf(fmaxf(t3, t4), s_acc[3][3]));
        mx = fmaxf(mx, __shfl_xor(mx, 16));
        mx = fmaxf(mx, __shfl_xor(mx, 32));

        // T13 defer-max (exp2 domain, THR=8); Ol rescales with O
        if (!__all(mx <= m_i + 8.0f)) {
            const float mnew  = fmaxf(m_i, mx);
            const float alpha = exp2f(m_i - mnew);   // exp2(-inf)=0 first tile
            #pragma unroll
            for (int nt = 0; nt < 4; ++nt) {
                O[nt][0] *= alpha; O[nt][1] *= alpha;
                O[nt][2] *= alpha; O[nt][3] *= alpha;
            }
            Ol[0] *= alpha; Ol[1] *= alpha; Ol[2] *= alpha; Ol[3] *= alpha;
            m_i = mnew;
        }

        float p[16];
        #pragma unroll
        for (int nt = 0; nt < 4; ++nt)
            #pragma unroll
            for (int reg = 0; reg < 4; ++reg)
                p[nt * 4 + reg] = exp2f(s_acc[nt][reg] - m_i);  // masked -> 0

        #pragma unroll
        for (int nt = 0; nt < 4; ++nt) {
            bf16x4 pv = { (bf16)p[nt * 4 + 0], (bf16)p[nt * 4 + 1],
                          (bf16)p[nt * 4 + 2], (bf16)p[nt * 4 + 3] };
            *(bf16x4*)&PS[w][l15 * 64 + (((nt << 4) + (quad << 2)) ^ sw8)] = pv;
        }

        // O^T += Vt P^T  (A=Vt rows h, B=P rows q); ones-row MFMA -> row sums
        __builtin_amdgcn_s_setprio(1);
        #pragma unroll
        for (int s2i = 0; s2i < 2; ++s2i) {
            bf16x8 ap = *(const bf16x8*)&PS[w][l15 * 64 + (((s2i << 5) + (quad << 3)) ^ sw8)];
            Ol = __builtin_amdgcn_mfma_f32_16x16x32_bf16(ones, ap, Ol, 0, 0, 0);
            #pragma unroll
            for (int nt = 0; nt < 4; ++nt) {
                bf16x8 bv = *(const bf16x8*)&curVS[((nt << 4) + l15) * 64
                                                   + (((s2i << 5) + (quad << 3)) ^ sw8)];
                O[nt] = __builtin_amdgcn_mfma_f32_16x16x32_bf16(bv, ap, O[nt], 0, 0, 0);
            }
        }
        __builtin_amdgcn_s_setprio(0);

        // stage next tile into the other buffer; rotate mask regs
        if (!last) {
            const int nxt = cur ^ 1;
            *(bf16x8*)&KH[nxt][rS * 64 + cL] = nkh;
            *(bf16x8*)&KL[nxt][rS * 64 + cL] = nkl;
            *(bf16x8*)&VS[nxt][rS * 64 + cL] = nvv;
            mu0 = nm0; mu1 = nm1; mu2 = nm2; mu3 = nm3;
            __syncthreads();   // writes visible; all reads of buf[cur] done
            cur = nxt;
        }
    }

    // normalize + write AO (bf16, [B*T][N*H]); lane owns col q, rows h.
    // Ol regs all equal Σ_s p[s][q=l15] — every lane holds its own l.
    {
        const float inv = 1.0f / Ol[0];
        const size_t base = ((size_t)b * TT + qrow) * (NHD * HD) + (size_t)n * HD;
        #pragma unroll
        for (int nt = 0; nt < 4; ++nt) {
            bf16x4 o = { (bf16)(O[nt][0] * inv), (bf16)(O[nt][1] * inv),
                         (bf16)(O[nt][2] * inv), (bf16)(O[nt][3] * inv) };
            *(bf16x4*)(AO + base + (nt << 4) + (quad << 2)) = o;
        }
    }
}

// ---------------------------------------------------------------------------
extern "C" void kernel_launch(void* const* d_in, const int* in_sizes, int n_in,
                              void* d_out, int out_size, void* d_ws, size_t ws_size,
                              hipStream_t stream)
{
    const float* X   = (const float*)d_in[0];
    const int*   msk = (const int*)d_in[1];
    const float* wq  = (const float*)d_in[2];
    const float* bq  = (const float*)d_in[3];
    const float* wk  = (const float*)d_in[4];
    const float* bk  = (const float*)d_in[5];
    const float* wv  = (const float*)d_in[6];
    const float* bv  = (const float*)d_in[7];
    const float* wo  = (const float*)d_in[8];
    const float* bo  = (const float*)d_in[9];
    const float* pds = (const float*)d_in[10];
    float* out = (float*)d_out;

    bf16* ws   = (bf16*)d_ws;
    bf16* Xh   = ws;                      // 4M  (later aliased by AO)
    bf16* Xl   = ws + 4194304;            // 4M
    bf16* WQKh = ws + 8388608;            // 2M  [2048 nh'][1024 d]
    bf16* WQKl = ws + 10485760;           // 2M
    bf16* Wvh  = ws + 12582912;           // 1M  [nh][d]
    bf16* Wob  = ws + 13631488;           // 1M  [d][nh]
    bf16* Qhb  = ws + 14680064;           // 4M  [b][n][t][h]
    bf16* Qlb  = ws + 18874368;
    bf16* Khb  = ws + 23068672;
    bf16* Klb  = ws + 27262976;
    bf16* Vtb  = ws + 32505856;           // 4M [b][nh][t]
    bf16* AOb  = Xh;                      // alias: Xh dead after proj
    // additive mask lives in d_out (16 MB = out_size exactly); it is consumed
    // by attn_mfma BEFORE gemm_out overwrites d_out with the final result.
    bf16* madd = (bf16*)d_out;

    dim3 blk(256);

    prep_all<<<8192, blk, 0, stream>>>(X, wq, wk, wv, wo,
                                       Xh, Xl, WQKh, WQKl, Wvh, Wob);

    // fused QK + V projections + mask conversion (tail-fill)
    gemm_proj<<<5632, blk, 0, stream>>>(
        Xh, Xl, WQKh, WQKl, Wvh, bq, bk, bv, pds, msk,
        Qhb, Qlb, Khb, Klb, Vtb, madd);

    dim3 ga(TT / 128, BB * NHD);   // (16, 32)
    attn_mfma<<<ga, dim3(512), 0, stream>>>(
        Qhb, Qlb, Khb, Klb, Vtb, madd, AOb);

    // output projection: M=4096, N=1024, K=1024, fp32 out, 128x64 tiles
    gemm_out<<<dim3(16, 32), blk, 0, stream>>>(AOb, Wob, bo, out);
}

// Round 11
// 302.730 us; speedup vs baseline: 1.0276x; 1.0110x over previous
//
#include <hip/hip_runtime.h>
#include <math.h>

typedef __bf16 bf16;
typedef __attribute__((ext_vector_type(8))) __bf16 bf16x8;
typedef __attribute__((ext_vector_type(4))) __bf16 bf16x4;
typedef __attribute__((ext_vector_type(4))) float f32x4;

#define BB 2
#define TT 2048
#define DD 1024
#define NHD 16
#define HD 64
#define MM (BB*TT)          // 4096
#define LOG2E_F 1.442695041f
#define NEGINF_F (-1.0e9f)

// async global->LDS, 16B per lane; LDS dest must be wave-uniform base
__device__ __forceinline__ void gld16(const bf16* g, bf16* l)
{
    __builtin_amdgcn_global_load_lds(
        (const __attribute__((address_space(1))) unsigned int*)g,
        (__attribute__((address_space(3))) unsigned int*)l, 16, 0, 0);
}

// ---------------------------------------------------------------------------
// fused prep (8192 blocks): [0,4096) split_x; [4096,8192) weight
// transpose/convert. Mask conversion lives in gemm_proj tail blocks (R10).
// NOTE (R7 lesson): sigma(S) ~ 1500 in exp2 domain -> running max mandatory.
// ---------------------------------------------------------------------------
__global__ __launch_bounds__(256)
void prep_all(const float* __restrict__ X,
              const float* __restrict__ wq, const float* __restrict__ wk,
              const float* __restrict__ wv, const float* __restrict__ wo,
              bf16* __restrict__ Xh, bf16* __restrict__ Xl,
              bf16* __restrict__ qkh, bf16* __restrict__ qkl,
              bf16* __restrict__ vh, bf16* __restrict__ ob)
{
    __shared__ float tile[32][33];
    const int bid = blockIdx.x;
    const int t   = threadIdx.x;

    if (bid < 4096) {                         // split X -> hi/lo
        int i = bid * 256 + t;
        float4 v = ((const float4*)X)[i];
        float f[4] = {v.x, v.y, v.z, v.w};
        bf16x4 h, l;
        #pragma unroll
        for (int j = 0; j < 4; ++j) {
            bf16 hh = (bf16)f[j];
            h[j] = hh;
            l[j] = (bf16)(f[j] - (float)hh);
        }
        *(bf16x4*)(Xh + (size_t)i * 4) = h;
        *(bf16x4*)(Xl + (size_t)i * 4) = l;
        return;
    }
    {                                         // weights
        const int idx = bid - 4096;
        const int z   = idx >> 10;            // 0:wq 1:wk 2:wv 3:wo
        const int bx  = (idx & 31) << 5;      // nh block
        const int by  = ((idx >> 5) & 31) << 5;  // d block
        const int r   = t >> 3;
        const int c4  = (t & 7) << 2;
        if (z == 3) {
            float4 v = *(const float4*)(wo + (size_t)(by + r) * 1024 + bx + c4);
            bf16x4 o = { (bf16)v.x, (bf16)v.y, (bf16)v.z, (bf16)v.w };
            *(bf16x4*)(ob + (size_t)(by + r) * 1024 + bx + c4) = o;
            return;
        }
        const float* src = (z == 0) ? wq : ((z == 1) ? wk : wv);
        bf16* oh = (z == 0) ? qkh : ((z == 1) ? qkh + 1048576 : vh);
        bf16* ol = (z == 0) ? qkl : ((z == 1) ? qkl + 1048576 : nullptr);
        float4 v = *(const float4*)(src + (size_t)(by + r) * 1024 + bx + c4);
        tile[r][c4+0] = v.x; tile[r][c4+1] = v.y;
        tile[r][c4+2] = v.z; tile[r][c4+3] = v.w;
        __syncthreads();
        bf16x4 hv, lv;
        #pragma unroll
        for (int j = 0; j < 4; ++j) {
            float f = tile[c4 + j][r];
            bf16 h = (bf16)f;
            hv[j] = h;
            lv[j] = (bf16)(f - (float)h);
        }
        *(bf16x4*)(oh + (size_t)(bx + r) * 1024 + by + c4) = hv;
        if (ol)
            *(bf16x4*)(ol + (size_t)(bx + r) * 1024 + by + c4) = lv;
    }
}

// ---------------------------------------------------------------------------
// Fused projection GEMM + mask conversion (5632 blocks):
//  [0,1024): QK — 3-pass split (Xh*Wh + Xh*Wl + Xl*Wh), 128(bt)x64(nh'),
//            BK=32; col<1024 -> Q (scaled, exp2-domain), else K; hi/lo out.
//  [1024,1536): V — C^T = Wvh · Xh^T, 128(nh)x64(bt), out Vt + bias.
//  [1536,5632): mask -> additive bf16 (0 / -1e9) into d_out — tail-fill.
// XCD-swizzled (T1) within GEMM segments.
// ---------------------------------------------------------------------------
__global__ __launch_bounds__(256)
void gemm_proj(const bf16* __restrict__ Xh, const bf16* __restrict__ Xl,
               const bf16* __restrict__ Wh, const bf16* __restrict__ Wl,
               const bf16* __restrict__ Wvh,
               const float* __restrict__ bq, const float* __restrict__ bk,
               const float* __restrict__ bv, const float* __restrict__ pds,
               const int* __restrict__ m,
               bf16* __restrict__ oQh, bf16* __restrict__ oQl,
               bf16* __restrict__ oKh, bf16* __restrict__ oKl,
               bf16* __restrict__ oVt, bf16* __restrict__ madd)
{
    __shared__ bf16 SA[2][128 * 32];   // A hi/lo: 16 KB
    __shared__ bf16 SB[2][64 * 32];    // B hi/lo:  8 KB

    int bid = blockIdx.x;
    const int t = threadIdx.x;

    if (bid >= 1536) {                 // ---- fused mask conversion ----
        int i = (bid - 1536) * 256 + t;       // i < 1048576 (8 elems each)
        const int4* mp = (const int4*)m + (size_t)i * 2;
        int4 a  = mp[0];
        int4 b4 = mp[1];
        bf16x8 o;
        o[0] = (bf16)(a.x  ? 0.f : NEGINF_F);
        o[1] = (bf16)(a.y  ? 0.f : NEGINF_F);
        o[2] = (bf16)(a.z  ? 0.f : NEGINF_F);
        o[3] = (bf16)(a.w  ? 0.f : NEGINF_F);
        o[4] = (bf16)(b4.x ? 0.f : NEGINF_F);
        o[5] = (bf16)(b4.y ? 0.f : NEGINF_F);
        o[6] = (bf16)(b4.z ? 0.f : NEGINF_F);
        o[7] = (bf16)(b4.w ? 0.f : NEGINF_F);
        *(bf16x8*)(madd + (size_t)i * 8) = o;
        return;
    }

    // bijective XCD swizzle within each GEMM segment (8 XCDs)
    if (bid < 1024) bid = ((bid & 7) << 7) + (bid >> 3);
    else {
        int idx = bid - 1024;
        bid = 1024 + (((idx & 7) << 6) + (idx >> 3));
    }

    const int lane = t & 63;
    const int w    = t >> 6;
    const int quad = lane >> 4, l15 = lane & 15;
    const int wm   = (w >> 1) << 6;    // 0 / 64
    const int wn   = (w & 1)  << 5;    // 0 / 32

    const int jr0 = ((w * 2 + 0) << 4) + (lane >> 2);   // A rows, site 0
    const int jr1 = ((w * 2 + 1) << 4) + (lane >> 2);   // A rows, site 1
    const int jrB = (w << 4) + (lane >> 2);             // B rows (64)
    const int kch = (lane & 3) << 3;
    const int offA0 = (w * 2 + 0) * 512;
    const int offA1 = (w * 2 + 1) * 512;
    const int offB  = w * 512;

    if (bid < 1024) {
        // ---------------- QK path: 128(m:bt) x 64(n:nh') ----------------
        const int m0 = (bid >> 5) << 7;       // 32 m-tiles
        const int n0 = (bid & 31) << 6;       // 32 n-tiles

        const bf16* pAh0 = Xh + (size_t)(m0 + jr0) * DD + kch;
        const bf16* pAh1 = Xh + (size_t)(m0 + jr1) * DD + kch;
        const bf16* pAl0 = Xl + (size_t)(m0 + jr0) * DD + kch;
        const bf16* pAl1 = Xl + (size_t)(m0 + jr1) * DD + kch;
        const bf16* pBh  = Wh + (size_t)(n0 + jrB) * DD + kch;
        const bf16* pBl  = Wl + (size_t)(n0 + jrB) * DD + kch;

        f32x4 acc[4][2] = {};

        for (int k0 = 0; k0 < DD; k0 += 32) {
            __syncthreads();
            gld16(pAh0 + k0, SA[0] + offA0);  gld16(pAh1 + k0, SA[0] + offA1);
            gld16(pAl0 + k0, SA[1] + offA0);  gld16(pAl1 + k0, SA[1] + offA1);
            gld16(pBh  + k0, SB[0] + offB);
            gld16(pBl  + k0, SB[1] + offB);
            __syncthreads();

            bf16x8 ah[4], bh[2];
            #pragma unroll
            for (int mt = 0; mt < 4; ++mt)
                ah[mt] = *(const bf16x8*)(SA[0] + (wm + (mt << 4) + l15) * 32 + (quad << 3));
            #pragma unroll
            for (int nt = 0; nt < 2; ++nt)
                bh[nt] = *(const bf16x8*)(SB[0] + (wn + (nt << 4) + l15) * 32 + (quad << 3));
            #pragma unroll
            for (int mt = 0; mt < 4; ++mt)
                #pragma unroll
                for (int nt = 0; nt < 2; ++nt)
                    acc[mt][nt] = __builtin_amdgcn_mfma_f32_16x16x32_bf16(
                        ah[mt], bh[nt], acc[mt][nt], 0, 0, 0);

            bf16x8 bl[2];
            #pragma unroll
            for (int nt = 0; nt < 2; ++nt)
                bl[nt] = *(const bf16x8*)(SB[1] + (wn + (nt << 4) + l15) * 32 + (quad << 3));
            #pragma unroll
            for (int mt = 0; mt < 4; ++mt)
                #pragma unroll
                for (int nt = 0; nt < 2; ++nt)
                    acc[mt][nt] = __builtin_amdgcn_mfma_f32_16x16x32_bf16(
                        ah[mt], bl[nt], acc[mt][nt], 0, 0, 0);

            bf16x8 al[4];
            #pragma unroll
            for (int mt = 0; mt < 4; ++mt)
                al[mt] = *(const bf16x8*)(SA[1] + (wm + (mt << 4) + l15) * 32 + (quad << 3));
            #pragma unroll
            for (int mt = 0; mt < 4; ++mt)
                #pragma unroll
                for (int nt = 0; nt < 2; ++nt)
                    acc[mt][nt] = __builtin_amdgcn_mfma_f32_16x16x32_bf16(
                        al[mt], bh[nt], acc[mt][nt], 0, 0, 0);
        }

        #pragma unroll
        for (int nt = 0; nt < 2; ++nt) {
            const int col = n0 + wn + (nt << 4) + l15;
            const int isQ = (col < 1024);
            const int nh  = col & 1023;
            const int n   = nh >> 6, h = nh & 63;
            const float bcol = isQ ? bq[nh] : bk[nh];
            float s = 1.f;
            if (isQ) {
                float x  = pds[h];
                float sp = fmaxf(x, 0.f) + log1pf(expf(-fabsf(x)));  // softplus
                s = (LOG2E_F * LOG2E_F / 8.0f) * sp;  // exp2 domain
            }
            bf16* dH = isQ ? oQh : oKh;
            bf16* dL = isQ ? oQl : oKl;
            #pragma unroll
            for (int mt = 0; mt < 4; ++mt) {
                #pragma unroll
                for (int reg = 0; reg < 4; ++reg) {
                    const int row = m0 + wm + (mt << 4) + (quad << 2) + reg;
                    const int bi  = row >> 11;
                    const int tt  = row & (TT - 1);
                    float val = (acc[mt][nt][reg] + bcol) * s;
                    const size_t idx = (((size_t)bi * NHD + n) * TT + tt) * HD + h;
                    bf16 hi = (bf16)val;
                    dH[idx] = hi;
                    dL[idx] = (bf16)(val - (float)hi);
                }
            }
        }
    } else {
        // ---------------- V path: 128(m:nh) x 64(n:bt) ----------------
        const int idx = bid - 1024;
        const int m0  = (idx >> 6) << 7;      // 8 nh tiles
        const int n0  = (idx & 63) << 6;      // 64 bt tiles

        const bf16* Ap0 = Wvh + (size_t)(m0 + jr0) * DD + kch;
        const bf16* Ap1 = Wvh + (size_t)(m0 + jr1) * DD + kch;
        const bf16* Bp  = Xh  + (size_t)(n0 + jrB) * DD + kch;

        f32x4 acc[4][2] = {};

        for (int k0 = 0; k0 < DD; k0 += 32) {
            __syncthreads();
            gld16(Ap0 + k0, SA[0] + offA0);
            gld16(Ap1 + k0, SA[0] + offA1);
            gld16(Bp  + k0, SB[0] + offB);
            __syncthreads();
            bf16x8 af[4], bfm[2];
            #pragma unroll
            for (int mt = 0; mt < 4; ++mt)
                af[mt] = *(const bf16x8*)(SA[0] + (wm + (mt << 4) + l15) * 32 + (quad << 3));
            #pragma unroll
            for (int nt = 0; nt < 2; ++nt)
                bfm[nt] = *(const bf16x8*)(SB[0] + (wn + (nt << 4) + l15) * 32 + (quad << 3));
            #pragma unroll
            for (int mt = 0; mt < 4; ++mt)
                #pragma unroll
                for (int nt = 0; nt < 2; ++nt)
                    acc[mt][nt] = __builtin_amdgcn_mfma_f32_16x16x32_bf16(
                        af[mt], bfm[nt], acc[mt][nt], 0, 0, 0);
        }

        #pragma unroll
        for (int nt = 0; nt < 2; ++nt) {
            const int col = n0 + wn + (nt << 4) + l15;   // bt
            const int bi  = col >> 11;
            const int tt  = col & (TT - 1);
            #pragma unroll
            for (int mt = 0; mt < 4; ++mt) {
                #pragma unroll
                for (int reg = 0; reg < 4; ++reg) {
                    const int row = m0 + wm + (mt << 4) + (quad << 2) + reg;  // nh
                    float val = acc[mt][nt][reg] + bv[row];
                    oVt[((size_t)bi * 1024 + row) * TT + tt] = (bf16)val;
                }
            }
        }
    }
}

// ---------------------------------------------------------------------------
// Output projection GEMM (R11): 64x64 tiles, 1024 blocks = 4 blocks/CU
// (was 128x64 / 512 blocks / 2 per CU — same under-occupancy R8's counters
// showed on gemm_proj). 4 waves per block, each owns a 32x32 quadrant.
// ---------------------------------------------------------------------------
__global__ __launch_bounds__(256)
void gemm_out(const bf16* __restrict__ A, const bf16* __restrict__ Bt,
              const float* __restrict__ bias, float* __restrict__ oF)
{
    __shared__ bf16 As[64 * 32];
    __shared__ bf16 Bs[64 * 32];

    const int t    = threadIdx.x;
    const int lane = t & 63;
    const int w    = t >> 6;
    const int quad = lane >> 4, l15 = lane & 15;
    const int m0   = blockIdx.y << 6;
    const int n0   = blockIdx.x << 6;
    const int wm   = (w >> 1) << 5;    // 0 / 32
    const int wn   = (w & 1)  << 5;    // 0 / 32

    const int jr  = (w << 4) + (lane >> 2);   // 64 rows, wave-partitioned
    const int kch = (lane & 3) << 3;

    bf16* lA = As + w * 512;
    bf16* lB = Bs + w * 512;

    const bf16* Ap = A  + (size_t)(m0 + jr) * DD + kch;
    const bf16* Bp = Bt + (size_t)(n0 + jr) * DD + kch;

    f32x4 acc[2][2] = {};

    for (int k0 = 0; k0 < DD; k0 += 32) {
        __syncthreads();
        gld16(Ap + k0, lA);
        gld16(Bp + k0, lB);
        __syncthreads();
        bf16x8 af[2], bfm[2];
        #pragma unroll
        for (int mt = 0; mt < 2; ++mt)
            af[mt] = *(const bf16x8*)(As + (wm + (mt << 4) + l15) * 32 + (quad << 3));
        #pragma unroll
        for (int nt = 0; nt < 2; ++nt)
            bfm[nt] = *(const bf16x8*)(Bs + (wn + (nt << 4) + l15) * 32 + (quad << 3));
        #pragma unroll
        for (int mt = 0; mt < 2; ++mt)
            #pragma unroll
            for (int nt = 0; nt < 2; ++nt)
                acc[mt][nt] = __builtin_amdgcn_mfma_f32_16x16x32_bf16(
                    af[mt], bfm[nt], acc[mt][nt], 0, 0, 0);
    }

    #pragma unroll
    for (int nt = 0; nt < 2; ++nt) {
        const int col = n0 + wn + (nt << 4) + l15;
        const float bcol = bias[col];
        #pragma unroll
        for (int mt = 0; mt < 2; ++mt) {
            #pragma unroll
            for (int reg = 0; reg < 4; ++reg) {
                const int row = m0 + wm + (mt << 4) + (quad << 2) + reg;
                oF[(size_t)row * DD + col] = acc[mt][nt][reg] + bcol;
            }
        }
    }
}

// ---------------------------------------------------------------------------
// MFMA flash attention (512 thr, q-tile 128, 8 waves), double-buffered,
// one barrier per iter (R6 structure, PASS @102us). Running max + defer-max
// (mandatory: sigma(S)~1500 exp2-domain). Mask folded into MFMA accumulator
// via lane-direct loads; row-sum via ones-row MFMA; swizzle (T2); setprio
// (T5). Prefetch addresses are running pointers (strength reduction).
// ---------------------------------------------------------------------------
__global__ __launch_bounds__(512, 4)
void attn_mfma(const bf16* __restrict__ Qh, const bf16* __restrict__ Ql,
               const bf16* __restrict__ Kh, const bf16* __restrict__ Kl,
               const bf16* __restrict__ Vt,
               const bf16* __restrict__ Madd,
               bf16* __restrict__ AO)
{
    __shared__ bf16 KH[2][64 * 64];
    __shared__ bf16 KL[2][64 * 64];
    __shared__ bf16 VS[2][64 * 64];    // [h][s], swizzled
    __shared__ bf16 PS[8][16 * 64];    // per-wave P, swizzled (same-wave RW)

    const int t    = threadIdx.x;
    const int lane = t & 63;
    const int w    = t >> 6;           // 0..7
    const int quad = lane >> 4, l15 = lane & 15;
    const int bn   = blockIdx.y;
    const int b    = bn >> 4, n = bn & 15;
    const int q0   = blockIdx.x << 7;  // 128 q per block

    const bf16* Qbh = Qh + (size_t)bn * TT * HD;
    const bf16* Qbl = Ql + (size_t)bn * TT * HD;
    const bf16* Kbh = Kh + (size_t)bn * TT * HD;
    const bf16* Kbl = Kl + (size_t)bn * TT * HD;
    const bf16* Vtb = Vt + (size_t)bn * HD * TT;
    const bf16* Mb  = Madd + (size_t)b * TT * TT;

    // Q fragments (B-operand: n=q=l15, k=h) — registers, loaded once
    const int qrow = q0 + (w << 4) + l15;
    bf16x8 qfh[2], qfl[2];
    qfh[0] = *(const bf16x8*)(Qbh + (size_t)qrow * HD + (quad << 3));
    qfh[1] = *(const bf16x8*)(Qbh + (size_t)qrow * HD + 32 + (quad << 3));
    qfl[0] = *(const bf16x8*)(Qbl + (size_t)qrow * HD + (quad << 3));
    qfl[1] = *(const bf16x8*)(Qbl + (size_t)qrow * HD + 32 + (quad << 3));

    f32x4 O[4];                         // O^T: row h=nt*16+quad*4+reg, col q=l15
    #pragma unroll
    for (int i = 0; i < 4; ++i) O[i] = (f32x4){0.f,0.f,0.f,0.f};
    f32x4 Ol = (f32x4){0.f,0.f,0.f,0.f};   // row-sum accumulator (ones-row)
    float m_i = -INFINITY;

    const bf16 onev = (bf16)1.0f;
    const bf16x8 ones = { onev, onev, onev, onev, onev, onev, onev, onev };

    // staging map: lane handles row rS, GLOBAL chunk (t&7); LDS write chunk
    // is XOR-swizzled so each 8-lane group fills one full 128B row.
    const int rS = t >> 3;                          // 0..63
    const int cG = (t & 7) << 3;                    // global elem offset
    const int cL = (((t & 7) ^ (rS & 7)) << 3);     // swizzled LDS offset
    // fragment-read swizzle key: row&7 == l15&7
    const int sw8 = (l15 & 7) << 3;

    // lane-direct mask base: this lane's q row, quad's 4-elem group
    const bf16* mrow0 = Mb + (size_t)qrow * TT + (quad << 2);

    // ---- prologue: stage tile 0 ----
    {
        bf16x8 khv = *(const bf16x8*)(Kbh + (size_t)rS * HD + cG);
        bf16x8 klv = *(const bf16x8*)(Kbl + (size_t)rS * HD + cG);
        bf16x8 vv  = *(const bf16x8*)(Vtb + (size_t)rS * TT + cG);
        *(bf16x8*)&KH[0][rS * 64 + cL] = khv;
        *(bf16x8*)&KL[0][rS * 64 + cL] = klv;
        *(bf16x8*)&VS[0][rS * 64 + cL] = vv;
    }
    ushort4 mu0 = *(const ushort4*)(mrow0);
    ushort4 mu1 = *(const ushort4*)(mrow0 + 16);
    ushort4 mu2 = *(const ushort4*)(mrow0 + 32);
    ushort4 mu3 = *(const ushort4*)(mrow0 + 48);
    __syncthreads();

    // running prefetch pointers (start at tile 1), constant strides per iter
    const bf16* kp = Kbh + (size_t)(64 + rS) * HD + cG;
    const bf16* lp = Kbl + (size_t)(64 + rS) * HD + cG;
    const bf16* vp = Vtb + (size_t)rS * TT + 64 + cG;
    const bf16* mp = mrow0 + 64;

    int cur = 0;
    for (int it = 0; it < 32; ++it) {
        const int last = (it == 31);
        // issue next tile's loads NOW — latency hides under this tile's work
        bf16x8 nkh, nkl, nvv;
        ushort4 nm0, nm1, nm2, nm3;
        if (!last) {
            nkh = *(const bf16x8*)(kp);
            nkl = *(const bf16x8*)(lp);
            nvv = *(const bf16x8*)(vp);
            nm0 = *(const ushort4*)(mp);
            nm1 = *(const ushort4*)(mp + 16);
            nm2 = *(const ushort4*)(mp + 32);
            nm3 = *(const ushort4*)(mp + 48);
            kp += 64 * HD; lp += 64 * HD; vp += 64; mp += 64;
        }

        const bf16* curKH = &KH[cur][0];
        const bf16* curKL = &KL[cur][0];
        const bf16* curVS = &VS[cur][0];

        // s_acc init = additive mask (C-in of the MFMA)
        f32x4 s_acc[4];
        s_acc[0][0] = __uint_as_float((unsigned)mu0.x << 16);
        s_acc[0][1] = __uint_as_float((unsigned)mu0.y << 16);
        s_acc[0][2] = __uint_as_float((unsigned)mu0.z << 16);
        s_acc[0][3] = __uint_as_float((unsigned)mu0.w << 16);
        s_acc[1][0] = __uint_as_float((unsigned)mu1.x << 16);
        s_acc[1][1] = __uint_as_float((unsigned)mu1.y << 16);
        s_acc[1][2] = __uint_as_float((unsigned)mu1.z << 16);
        s_acc[1][3] = __uint_as_float((unsigned)mu1.w << 16);
        s_acc[2][0] = __uint_as_float((unsigned)mu2.x << 16);
        s_acc[2][1] = __uint_as_float((unsigned)mu2.y << 16);
        s_acc[2][2] = __uint_as_float((unsigned)mu2.z << 16);
        s_acc[2][3] = __uint_as_float((unsigned)mu2.w << 16);
        s_acc[3][0] = __uint_as_float((unsigned)mu3.x << 16);
        s_acc[3][1] = __uint_as_float((unsigned)mu3.y << 16);
        s_acc[3][2] = __uint_as_float((unsigned)mu3.z << 16);
        s_acc[3][3] = __uint_as_float((unsigned)mu3.w << 16);

        // S^T = K Q^T + M (rows s, cols q), split: Kh*Qh + Kl*Qh + Kh*Ql
        __builtin_amdgcn_s_setprio(1);
        #pragma unroll
        for (int k2 = 0; k2 < 2; ++k2) {
            #pragma unroll
            for (int nt = 0; nt < 4; ++nt) {
                const int ro = ((nt << 4) + l15) * 64;
                const int co = ((k2 << 5) + (quad << 3)) ^ sw8;
                bf16x8 bkh = *(const bf16x8*)&curKH[ro + co];
                bf16x8 bkl = *(const bf16x8*)&curKL[ro + co];
                s_acc[nt] = __builtin_amdgcn_mfma_f32_16x16x32_bf16(bkh, qfh[k2], s_acc[nt], 0, 0, 0);
                s_acc[nt] = __builtin_amdgcn_mfma_f32_16x16x32_bf16(bkl, qfh[k2], s_acc[nt], 0, 0, 0);
                s_acc[nt] = __builtin_amdgcn_mfma_f32_16x16x32_bf16(bkh, qfl[k2], s_acc[nt], 0, 0, 0);
            }
        }
        __builtin_amdgcn_s_setprio(0);

        // per-lane softmax over s — mask already inside s_acc.
        float t0 = fmaxf(fmaxf(s_acc[0][0], s_acc[0][1]), s_acc[0][2]);
        float t1 = fmaxf(fmaxf(s_acc[0][3], s_acc[1][0]), s_acc[1][1]);
        float t2 = fmaxf(fmaxf(s_acc[1][2], s_acc[1][3]), s_acc[2][0]);
        float t3 = fmaxf(fmaxf(s_acc[2][1], s_acc[2][2]), s_acc[2][3]);
        float t4 = fmaxf(fmaxf(s_acc[3][0], s_acc[3][1]), s_acc[3][2]);
        float mx = fmaxf(fmaxf(fmaxf(t0, t1), t2),
                         fmaxf(fmaxf(t3, t4), s_acc[3][3]));
        mx = fmaxf(mx, __shfl_xor(mx, 16));
        mx = fmaxf(mx, __shfl_xor(mx, 32));

        // T13 defer-max (exp2 domain, THR=8); Ol rescales with O
        if (!__all(mx <= m_i + 8.0f)) {
            const float mnew  = fmaxf(m_i, mx);
            const float alpha = exp2f(m_i - mnew);   // exp2(-inf)=0 first tile
            #pragma unroll
            for (int nt = 0; nt < 4; ++nt) {
                O[nt][0] *= alpha; O[nt][1] *= alpha;
                O[nt][2] *= alpha; O[nt][3] *= alpha;
            }
            Ol[0] *= alpha; Ol[1] *= alpha; Ol[2] *= alpha; Ol[3] *= alpha;
            m_i = mnew;
        }

        float p[16];
        #pragma unroll
        for (int nt = 0; nt < 4; ++nt)
            #pragma unroll
            for (int reg = 0; reg < 4; ++reg)
                p[nt * 4 + reg] = exp2f(s_acc[nt][reg] - m_i);  // masked -> 0

        #pragma unroll
        for (int nt = 0; nt < 4; ++nt) {
            bf16x4 pv = { (bf16)p[nt * 4 + 0], (bf16)p[nt * 4 + 1],
                          (bf16)p[nt * 4 + 2], (bf16)p[nt * 4 + 3] };
            *(bf16x4*)&PS[w][l15 * 64 + (((nt << 4) + (quad << 2)) ^ sw8)] = pv;
        }

        // O^T += Vt P^T  (A=Vt rows h, B=P rows q); ones-row MFMA -> row sums
        __builtin_amdgcn_s_setprio(1);
        #pragma unroll
        for (int s2i = 0; s2i < 2; ++s2i) {
            bf16x8 ap = *(const bf16x8*)&PS[w][l15 * 64 + (((s2i << 5) + (quad << 3)) ^ sw8)];
            Ol = __builtin_amdgcn_mfma_f32_16x16x32_bf16(ones, ap, Ol, 0, 0, 0);
            #pragma unroll
            for (int nt = 0; nt < 4; ++nt) {
                bf16x8 bv = *(const bf16x8*)&curVS[((nt << 4) + l15) * 64
                                                   + (((s2i << 5) + (quad << 3)) ^ sw8)];
                O[nt] = __builtin_amdgcn_mfma_f32_16x16x32_bf16(bv, ap, O[nt], 0, 0, 0);
            }
        }
        __builtin_amdgcn_s_setprio(0);

        // stage next tile into the other buffer; rotate mask regs
        if (!last) {
            const int nxt = cur ^ 1;
            *(bf16x8*)&KH[nxt][rS * 64 + cL] = nkh;
            *(bf16x8*)&KL[nxt][rS * 64 + cL] = nkl;
            *(bf16x8*)&VS[nxt][rS * 64 + cL] = nvv;
            mu0 = nm0; mu1 = nm1; mu2 = nm2; mu3 = nm3;
            __syncthreads();   // writes visible; all reads of buf[cur] done
            cur = nxt;
        }
    }

    // normalize + write AO (bf16, [B*T][N*H]); lane owns col q, rows h.
    // Ol regs all equal Σ_s p[s][q=l15] — every lane holds its own l.
    {
        const float inv = 1.0f / Ol[0];
        const size_t base = ((size_t)b * TT + qrow) * (NHD * HD) + (size_t)n * HD;
        #pragma unroll
        for (int nt = 0; nt < 4; ++nt) {
            bf16x4 o = { (bf16)(O[nt][0] * inv), (bf16)(O[nt][1] * inv),
                         (bf16)(O[nt][2] * inv), (bf16)(O[nt][3] * inv) };
            *(bf16x4*)(AO + base + (nt << 4) + (quad << 2)) = o;
        }
    }
}

// ---------------------------------------------------------------------------
extern "C" void kernel_launch(void* const* d_in, const int* in_sizes, int n_in,
                              void* d_out, int out_size, void* d_ws, size_t ws_size,
                              hipStream_t stream)
{
    const float* X   = (const float*)d_in[0];
    const int*   msk = (const int*)d_in[1];
    const float* wq  = (const float*)d_in[2];
    const float* bq  = (const float*)d_in[3];
    const float* wk  = (const float*)d_in[4];
    const float* bk  = (const float*)d_in[5];
    const float* wv  = (const float*)d_in[6];
    const float* bv  = (const float*)d_in[7];
    const float* wo  = (const float*)d_in[8];
    const float* bo  = (const float*)d_in[9];
    const float* pds = (const float*)d_in[10];
    float* out = (float*)d_out;

    bf16* ws   = (bf16*)d_ws;
    bf16* Xh   = ws;                      // 4M  (later aliased by AO)
    bf16* Xl   = ws + 4194304;            // 4M
    bf16* WQKh = ws + 8388608;            // 2M  [2048 nh'][1024 d]
    bf16* WQKl = ws + 10485760;           // 2M
    bf16* Wvh  = ws + 12582912;           // 1M  [nh][d]
    bf16* Wob  = ws + 13631488;           // 1M  [d][nh]
    bf16* Qhb  = ws + 14680064;           // 4M  [b][n][t][h]
    bf16* Qlb  = ws + 18874368;
    bf16* Khb  = ws + 23068672;
    bf16* Klb  = ws + 27262976;
    bf16* Vtb  = ws + 32505856;           // 4M [b][nh][t]
    bf16* AOb  = Xh;                      // alias: Xh dead after proj
    // additive mask lives in d_out (16 MB = out_size exactly); it is consumed
    // by attn_mfma BEFORE gemm_out overwrites d_out with the final result.
    bf16* madd = (bf16*)d_out;

    dim3 blk(256);

    prep_all<<<8192, blk, 0, stream>>>(X, wq, wk, wv, wo,
                                       Xh, Xl, WQKh, WQKl, Wvh, Wob);

    // fused QK + V projections + mask conversion (tail-fill)
    gemm_proj<<<5632, blk, 0, stream>>>(
        Xh, Xl, WQKh, WQKl, Wvh, bq, bk, bv, pds, msk,
        Qhb, Qlb, Khb, Klb, Vtb, madd);

    dim3 ga(TT / 128, BB * NHD);   // (16, 32)
    attn_mfma<<<ga, dim3(512), 0, stream>>>(
        Qhb, Qlb, Khb, Klb, Vtb, madd, AOb);

    // output projection: M=4096, N=1024, K=1024, fp32 out, 64x64 tiles
    gemm_out<<<dim3(16, 64), blk, 0, stream>>>(AOb, Wob, bo, out);
}